// Round 1
// baseline (5053.128 us; speedup 1.0000x reference)
//
#include <hip/hip_runtime.h>

#define NN 256
#define NP1 257
#define BIGF 1e9f

// Zero-fill the output (harness poisons d_out; we must produce exact 0/1).
__global__ void lap_zero(float* __restrict__ out) {
    int idx = blockIdx.x * blockDim.x + threadIdx.x;
    if (idx < NN * NN) out[idx] = 0.0f;
}

// Exact Jonker-Volgenant shortest augmenting path LAP, bit-faithful port of
// the reference. Single wave (64 lanes); lanes own strided column slices.
__global__ __launch_bounds__(64) void lap_solve(const float* __restrict__ C,
                                                float* __restrict__ out) {
    __shared__ float u[NP1];     // row duals (1-indexed, 0 = dummy)
    __shared__ float v[NP1];     // col duals
    __shared__ float minv[NP1];  // tentative shortest-path reduced costs
    __shared__ int   p[NP1];     // p[j] = row matched to col j (0 = free)
    __shared__ int   way[NP1];   // predecessor column on the path
    __shared__ int   used[NP1];  // visited columns

    const int lane = threadIdx.x;  // 0..63

    for (int j = lane; j < NP1; j += 64) {
        u[j] = 0.0f; v[j] = 0.0f; p[j] = 0;
    }
    __syncthreads();

    for (int i = 1; i <= NN; ++i) {
        if (lane == 0) p[0] = i;
        for (int j = lane; j < NP1; j += 64) {
            used[j] = 0; minv[j] = BIGF; way[j] = 0;
        }
        __syncthreads();

        int j0 = 0;
        while (true) {
            int i0 = p[j0];                 // uniform LDS read
            if (lane == 0) used[j0] = 1;
            __syncthreads();

            float ui0 = u[i0];
            const float* crow = C + (i0 - 1) * NN;

            // scan: update minv/way, find argmin of masked (first-index ties)
            float bestv = BIGF;
            int   bestj = NP1;              // sentinel > any real index
            for (int j = lane; j < NP1; j += 64) {
                int   us = used[j];
                float mv = minv[j];
                if (j > 0) {
                    // exact op order of reference: (C1[i0][j] - u[i0]) - v[j]
                    float cur = (crow[j - 1] - ui0) - v[j];
                    if (!us && cur < mv) { mv = cur; minv[j] = cur; way[j] = j0; }
                }
                float masked = us ? BIGF : mv;
                // strict < keeps lowest j within this lane's increasing slice
                if (masked < bestv) { bestv = masked; bestj = j; }
            }
            // wave argmin with lowest-index tie-break
            for (int off = 32; off; off >>= 1) {
                float ov = __shfl_xor(bestv, off, 64);
                int   oj = __shfl_xor(bestj, off, 64);
                if (ov < bestv || (ov == bestv && oj < bestj)) {
                    bestv = ov; bestj = oj;
                }
            }
            float delta = bestv;
            int   j1    = bestj;

            __syncthreads();
            // dual updates; matched rows p[j] of used cols are distinct -> no race
            for (int j = lane; j < NP1; j += 64) {
                if (used[j]) {
                    u[p[j]] += delta;
                    v[j]    -= delta;
                } else {
                    minv[j] -= delta;
                }
            }
            __syncthreads();

            j0 = j1;
            if (p[j0] == 0) break;          // reached a free column
        }

        // augment along the alternating path back to dummy column 0
        if (lane == 0) {
            int j = j0;
            while (j != 0) {
                int jn = way[j];
                p[j] = p[jn];
                j = jn;
            }
        }
        __syncthreads();
    }

    // emit 0/1 labelling: out[p[j]-1, j-1] = 1
    for (int j = lane + 1; j < NP1; j += 64) {
        int r = p[j] - 1;
        out[r * NN + (j - 1)] = 1.0f;
    }
}

extern "C" void kernel_launch(void* const* d_in, const int* in_sizes, int n_in,
                              void* d_out, int out_size, void* d_ws, size_t ws_size,
                              hipStream_t stream) {
    const float* C   = (const float*)d_in[0];
    float*       out = (float*)d_out;
    hipLaunchKernelGGL(lap_zero, dim3((NN * NN + 255) / 256), dim3(256), 0, stream, out);
    hipLaunchKernelGGL(lap_solve, dim3(1), dim3(64), 0, stream, C, out);
}

// Round 4
// 1434.632 us; speedup vs baseline: 3.5222x; 3.5222x over previous
//
#include <hip/hip_runtime.h>

#define NN 256
#define BIGF 1e9f
#define NROWS_LDS 60              // C rows cached in static LDS (exact f32)

__global__ void lap_zero(float* __restrict__ out) {
    int idx = blockIdx.x * blockDim.x + threadIdx.x;
    if (idx < NN * NN) out[idx] = 0.0f;
}

// One DPP min stage. old = x itself, so ANY invalid-lane/bound-ctrl/mask
// behavior degrades to fmin(x,x) = x (identity) — cannot corrupt the min.
template <int CTRL>
__device__ __forceinline__ float dpp_fmin(float x) {
    int t = __builtin_amdgcn_update_dpp(__float_as_int(x), __float_as_int(x),
                                        CTRL, 0xf, 0xf, false);
    return fminf(x, __int_as_float(t));
}

// Wave-64 min, result broadcast to all lanes via readlane(63) -> SGPR.
__device__ __forceinline__ float wave_min_bcast(float x) {
    x = dpp_fmin<0x111>(x);  // row_shr:1
    x = dpp_fmin<0x112>(x);  // row_shr:2
    x = dpp_fmin<0x114>(x);  // row_shr:4
    x = dpp_fmin<0x118>(x);  // row_shr:8
    x = dpp_fmin<0x142>(x);  // row_bcast:15
    x = dpp_fmin<0x143>(x);  // row_bcast:31  -> lane 63 holds global min
    return __int_as_float(__builtin_amdgcn_readlane(__float_as_int(x), 63));
}

extern "C" __global__ __launch_bounds__(64)
void lap_solve(const float* __restrict__ C, float* __restrict__ out) {
    __shared__ float rowc[NROWS_LDS * 256];  // 61440 B
    __shared__ float u[260];                 // row duals (1-indexed; 0 dummy)
    __shared__ float dlog[304];              // per-step delta log

    const int lane = threadIdx.x;
    const int base = lane * 4;               // owns columns base+1 .. base+4

    {   // stage first NROWS_LDS rows of C into LDS (exact copy)
        const float4* src = (const float4*)C;
        float4*       dst = (float4*)rowc;
        for (int idx = lane; idx < NROWS_LDS * 64; idx += 64) dst[idx] = src[idx];
    }
    for (int j = lane; j <= NN; j += 64) u[j] = 0.0f;
    __syncthreads();

    // per-lane column state, all statically indexed -> registers
    float v0 = 0.f, v1 = 0.f, v2 = 0.f, v3 = 0.f;   // col duals
    int   p0 = 0,  p1 = 0,  p2 = 0,  p3 = 0;        // matched row (0 = free)

    for (int i = 1; i <= NN; ++i) {
        float m0 = BIGF, m1 = BIGF, m2 = BIGF, m3 = BIGF;  // minv
        int   w0 = 0, w1 = 0, w2 = 0, w3 = 0;              // way (pred col)
        int   t0 = 0, t1 = 0, t2 = 0, t3 = 0;              // step marked used (0 = unused)

        int j0 = 0, i0 = i, t = 1, jF = 0;

        // Dijkstra loop: provably <= 257 steps; hard-bounded for hang safety.
        for (int guard = 0; guard < 300; ++guard) {
            float4 q;
            if (i0 <= NROWS_LDS) q = *(const float4*)&rowc[(i0 - 1) * 256 + base];
            else                 q = *(const float4*)&C[(i0 - 1) * 256 + base];
            float u0 = u[i0];   // frozen start-of-iteration value (invariant)

            // cur = (C1[i0][j] - u[i0]) - v[j], exact reference op order
            float c0 = (q.x - u0) - v0;
            float c1 = (q.y - u0) - v1;
            float c2 = (q.z - u0) - v2;
            float c3 = (q.w - u0) - v3;
            if (t0 == 0 && c0 < m0) { m0 = c0; w0 = j0; }
            if (t1 == 0 && c1 < m1) { m1 = c1; w1 = j0; }
            if (t2 == 0 && c2 < m2) { m2 = c2; w2 = j0; }
            if (t3 == 0 && c3 < m3) { m3 = c3; w3 = j0; }
            float k0 = t0 ? BIGF : m0;
            float k1 = t1 ? BIGF : m1;
            float k2 = t2 ? BIGF : m2;
            float k3 = t3 ? BIGF : m3;

            // local argmin (strict < keeps lowest slot = lowest j)
            float bv = k0; int bk = 0;
            if (k1 < bv) { bv = k1; bk = 1; }
            if (k2 < bv) { bv = k2; bk = 2; }
            if (k3 < bv) { bv = k3; bk = 3; }
            int rc = (bk == 0) ? p0 : (bk == 1) ? p1 : (bk == 2) ? p2 : p3;
            int bj = base + bk + 1;

            // wave min (DPP) + lowest-lane winner = lowest j (argmin first-index)
            float gmin = wave_min_bcast(bv);
            unsigned long long bal = __ballot(bv == gmin);
            int wl  = (int)__builtin_ctzll(bal | 0x8000000000000000ULL); // defined even if bal==0
            int j1  = __builtin_amdgcn_readlane(bj, wl);
            int i0n = __builtin_amdgcn_readlane(rc, wl);

            float delta = gmin;
            if (lane == 0) dlog[t] = delta;

            // minv -= delta for currently-unused (includes j1, per reference)
            if (t0 == 0) m0 -= delta;
            if (t1 == 0) m1 -= delta;
            if (t2 == 0) m2 -= delta;
            if (t3 == 0) m3 -= delta;

            // j1 becomes used at step t+1 (reference marks at top of next step)
            int oj = (j1 - 1) >> 2, sj = (j1 - 1) & 3;
            if (oj == lane) {
                if (sj == 0) t0 = t + 1;
                else if (sj == 1) t1 = t + 1;
                else if (sj == 2) t2 = t + 1;
                else t3 = t + 1;
            }

            ++t; j0 = j1; i0 = i0n;
            if (i0n == 0) { jF = j1; break; }   // reached a free column
        }
        const int T = t - 1;

        __syncthreads();                        // dlog visible

        // Exact dual replay: identical add/sub sequence per element as the
        // reference's per-step updates -> bit-identical u, v.
        float a0 = 0.f, a1 = 0.f, a2 = 0.f, a3 = 0.f;
        if (t0) a0 = u[p0];
        if (t1) a1 = u[p1];
        if (t2) a2 = u[p2];
        if (t3) a3 = u[p3];
        float ui = u[i];                        // row i used from step 1 (col 0)
        for (int s = 1; s <= T; ++s) {
            float d = dlog[s];
            if (t0 && s >= t0) { a0 += d; v0 -= d; }
            if (t1 && s >= t1) { a1 += d; v1 -= d; }
            if (t2 && s >= t2) { a2 += d; v2 -= d; }
            if (t3 && s >= t3) { a3 += d; v3 -= d; }
            ui += d;
        }
        if (t0) u[p0] = a0;                     // distinct rows -> no conflicts
        if (t1) u[p1] = a1;
        if (t2) u[p2] = a2;
        if (t3) u[p3] = a3;
        if (lane == 0) u[i] = ui;

        // augment: p[j] = p[way[j]] walking back to dummy col 0 (bounded)
        int j = jF;
        for (int g2 = 0; g2 < 300 && j != 0; ++g2) {
            int oj = (j - 1) >> 2, sj = (j - 1) & 3;
            int wsel = (sj == 0) ? w0 : (sj == 1) ? w1 : (sj == 2) ? w2 : w3;
            int jn = __shfl(wsel, oj, 64);
            int pn;
            if (jn == 0) pn = i;
            else {
                int on = (jn - 1) >> 2, sn = (jn - 1) & 3;
                int ps = (sn == 0) ? p0 : (sn == 1) ? p1 : (sn == 2) ? p2 : p3;
                pn = __shfl(ps, on, 64);
            }
            if (lane == oj) {
                if (sj == 0) p0 = pn; else if (sj == 1) p1 = pn;
                else if (sj == 2) p2 = pn; else p3 = pn;
            }
            j = jn;
        }
        __syncthreads();                        // u stores visible next iter
    }

    // emit 0/1 labelling: out[p[j]-1, j-1] = 1
    if (p0) out[(p0 - 1) * NN + base + 0] = 1.0f;
    if (p1) out[(p1 - 1) * NN + base + 1] = 1.0f;
    if (p2) out[(p2 - 1) * NN + base + 2] = 1.0f;
    if (p3) out[(p3 - 1) * NN + base + 3] = 1.0f;
}

extern "C" void kernel_launch(void* const* d_in, const int* in_sizes, int n_in,
                              void* d_out, int out_size, void* d_ws, size_t ws_size,
                              hipStream_t stream) {
    const float* C   = (const float*)d_in[0];
    float*       out = (float*)d_out;
    hipLaunchKernelGGL(lap_zero, dim3((NN * NN + 255) / 256), dim3(256), 0, stream, out);
    hipLaunchKernelGGL(lap_solve, dim3(1), dim3(64), 0, stream, C, out);
}

// Round 5
// 1292.387 us; speedup vs baseline: 3.9099x; 1.1101x over previous
//
#include <hip/hip_runtime.h>

#define NN 256
#define BIGF 1e9f
#define NROWS_LDS 152                       // C rows cached in dynamic LDS (exact f32)
#define SMEM_BYTES (NROWS_LDS * 256 * 4)    // 155648 B <= 160 KiB

// One DPP min stage. old = x itself, so any invalid-lane behavior degrades to
// fmin(x,x) = identity — cannot corrupt the min. (Verified passing in round 4.)
template <int CTRL>
__device__ __forceinline__ float dpp_fmin(float x) {
    int t = __builtin_amdgcn_update_dpp(__float_as_int(x), __float_as_int(x),
                                        CTRL, 0xf, 0xf, false);
    return fminf(x, __int_as_float(t));
}

// Wave-64 min, broadcast to all lanes through lane 63.
__device__ __forceinline__ float wave_min_bcast(float x) {
    x = dpp_fmin<0x111>(x);  // row_shr:1
    x = dpp_fmin<0x112>(x);  // row_shr:2
    x = dpp_fmin<0x114>(x);  // row_shr:4
    x = dpp_fmin<0x118>(x);  // row_shr:8
    x = dpp_fmin<0x142>(x);  // row_bcast:15
    x = dpp_fmin<0x143>(x);  // row_bcast:31
    return __int_as_float(__builtin_amdgcn_readlane(__float_as_int(x), 63));
}

extern "C" __global__ __launch_bounds__(64)
void lap_solve(const float* __restrict__ C, float* __restrict__ out) {
    extern __shared__ float rowc[];          // [NROWS_LDS][256]
    const int lane = threadIdx.x;
    const int base = lane * 4;               // owns 1-based columns base+1..base+4

    {   // stage rows 1..NROWS_LDS of C into LDS (exact f32 copy)
        const float4* src = (const float4*)C;
        float4*       dst = (float4*)rowc;
        #pragma unroll 8
        for (int idx = lane; idx < NROWS_LDS * 64; idx += 64) dst[idx] = src[idx];
    }
    __syncthreads();   // also drains LDS writes before reads (single wave)

    // All per-column state in registers (statically indexed):
    float v0 = 0.f, v1 = 0.f, v2 = 0.f, v3 = 0.f;   // col duals v[j]
    float a0 = 0.f, a1 = 0.f, a2 = 0.f, a3 = 0.f;   // a_k = u[p_k] (row dual of matched row)
    int   p0 = 0,  p1 = 0,  p2 = 0,  p3 = 0;        // matched row per col (0 = free)

    for (int i = 1; i <= NN; ++i) {
        float m0 = BIGF, m1 = BIGF, m2 = BIGF, m3 = BIGF;  // minv
        int   w0 = 0, w1 = 0, w2 = 0, w3 = 0;              // way (pred col)
        int   q0 = 0, q1 = 0, q2 = 0, q3 = 0;              // used flags
        float ui = 0.0f;            // u[i] accumulator (row i fresh => starts 0)
        float u0 = 0.0f;            // u[i0] for the current step (row i => 0)
        int   j0 = 0, i0 = i, jF = 0;

        // Dijkstra: provably <= 257 steps; bounded for hang safety.
        for (int guard = 0; guard < 300; ++guard) {
            float4 r;
            if (i0 <= NROWS_LDS) r = *(const float4*)&rowc[(i0 - 1) * 256 + base];
            else                 r = *(const float4*)&C[(i0 - 1) * 256 + base];

            // cur = (C1[i0][j] - u[i0]) - v[j]   (exact reference op order;
            // u[i0], v[j] are iteration-start values — proved invariant)
            float c0 = (r.x - u0) - v0;
            float c1 = (r.y - u0) - v1;
            float c2 = (r.z - u0) - v2;
            float c3 = (r.w - u0) - v3;
            if (!q0 && c0 < m0) { m0 = c0; w0 = j0; }
            if (!q1 && c1 < m1) { m1 = c1; w1 = j0; }
            if (!q2 && c2 < m2) { m2 = c2; w2 = j0; }
            if (!q3 && c3 < m3) { m3 = c3; w3 = j0; }
            float k0 = q0 ? BIGF : m0;
            float k1 = q1 ? BIGF : m1;
            float k2 = q2 ? BIGF : m2;
            float k3 = q3 ? BIGF : m3;

            // local argmin over 4 slots (strict < keeps lowest j)
            float bv = k0; int bk = 0;
            if (k1 < bv) { bv = k1; bk = 1; }
            if (k2 < bv) { bv = k2; bk = 2; }
            if (k3 < bv) { bv = k3; bk = 3; }
            int   rc = (bk == 0) ? p0 : (bk == 1) ? p1 : (bk == 2) ? p2 : p3;
            float ra = (bk == 0) ? a0 : (bk == 1) ? a1 : (bk == 2) ? a2 : a3;
            int   bj = base + bk + 1;

            // wave min + lowest-lane winner = argmin first-index semantics
            float gmin = wave_min_bcast(bv);
            unsigned long long bal = __ballot(bv == gmin);
            int wl  = (int)__builtin_ctzll(bal | 0x8000000000000000ULL);
            int j1  = __builtin_amdgcn_readlane(bj, wl);
            int i0n = __builtin_amdgcn_readlane(rc, wl);
            int unb = __builtin_amdgcn_readlane(__float_as_int(ra), wl);

            // exact per-step dual updates (same op sequence as reference):
            // used cols: u[p_k] += delta, v_k -= delta; unused: minv -= delta.
            float delta = gmin;
            if (q0) { a0 += delta; v0 -= delta; } else { m0 -= delta; }
            if (q1) { a1 += delta; v1 -= delta; } else { m1 -= delta; }
            if (q2) { a2 += delta; v2 -= delta; } else { m2 -= delta; }
            if (q3) { a3 += delta; v3 -= delta; } else { m3 -= delta; }
            ui += delta;                        // col 0 (row i) used every step

            // winner becomes used starting NEXT step (reference marks at top)
            int oj = (j1 - 1) >> 2, sj = (j1 - 1) & 3;
            if (lane == oj) {
                if (sj == 0) q0 = 1; else if (sj == 1) q1 = 1;
                else if (sj == 2) q2 = 1; else q3 = 1;
            }

            j0 = j1; i0 = i0n; u0 = __int_as_float(unb);
            if (i0n == 0) { jF = j1; break; }   // winner column is free
        }

        // augment: p[j] = p[way[j]] back to dummy col 0; carry the matched
        // row's final dual along so a_k = u[p_k] stays exact.
        int j = jF;
        for (int g2 = 0; g2 < 300 && j != 0; ++g2) {
            int oj = (j - 1) >> 2, sj = (j - 1) & 3;
            int wsel = (sj == 0) ? w0 : (sj == 1) ? w1 : (sj == 2) ? w2 : w3;
            int jn = __shfl(wsel, oj, 64);
            int pn; float an;
            if (jn == 0) { pn = i; an = ui; }
            else {
                int on = (jn - 1) >> 2, sn = (jn - 1) & 3;
                int   ps = (sn == 0) ? p0 : (sn == 1) ? p1 : (sn == 2) ? p2 : p3;
                float as = (sn == 0) ? a0 : (sn == 1) ? a1 : (sn == 2) ? a2 : a3;
                pn = __shfl(ps, on, 64);
                an = __shfl(as, on, 64);
            }
            if (lane == oj) {
                if (sj == 0) { p0 = pn; a0 = an; }
                else if (sj == 1) { p1 = pn; a1 = an; }
                else if (sj == 2) { p2 = pn; a2 = an; }
                else { p3 = pn; a3 = an; }
            }
            j = jn;
        }
    }

    // emit 0/1 labelling: out[p[j]-1, j-1] = 1  (out pre-zeroed by memset)
    if (p0) out[(p0 - 1) * NN + base + 0] = 1.0f;
    if (p1) out[(p1 - 1) * NN + base + 1] = 1.0f;
    if (p2) out[(p2 - 1) * NN + base + 2] = 1.0f;
    if (p3) out[(p3 - 1) * NN + base + 3] = 1.0f;
}

extern "C" void kernel_launch(void* const* d_in, const int* in_sizes, int n_in,
                              void* d_out, int out_size, void* d_ws, size_t ws_size,
                              hipStream_t stream) {
    const float* C   = (const float*)d_in[0];
    float*       out = (float*)d_out;

    static_assert(SMEM_BYTES <= 160 * 1024, "LDS budget");
    // Host-side, idempotent, not a stream op — safe under graph capture.
    (void)hipFuncSetAttribute((const void*)lap_solve,
                              hipFuncAttributeMaxDynamicSharedMemorySize,
                              SMEM_BYTES);

    hipMemsetAsync(out, 0, NN * NN * sizeof(float), stream);
    lap_solve<<<dim3(1), dim3(64), SMEM_BYTES, stream>>>(C, out);
}

// Round 6
// 1034.508 us; speedup vs baseline: 4.8846x; 1.2493x over previous
//
#include <hip/hip_runtime.h>

#define NN 256
#define BIGF 1e9f
#define NROWS_LDS 152                       // C rows cached in dynamic LDS (exact f32)
#define SMEM_BYTES (NROWS_LDS * 256 * 4)    // 155648 B <= 160 KiB

// One DPP min stage; old = x so any invalid-lane behavior is fmin(x,x) = identity.
template <int CTRL>
__device__ __forceinline__ float dpp_fmin(float x) {
    int t = __builtin_amdgcn_update_dpp(__float_as_int(x), __float_as_int(x),
                                        CTRL, 0xf, 0xf, false);
    return fminf(x, __int_as_float(t));
}

// Wave-64 min broadcast to all lanes through lane 63. (Verified rounds 4-5.)
__device__ __forceinline__ float wave_min_bcast(float x) {
    x = dpp_fmin<0x111>(x);  // row_shr:1
    x = dpp_fmin<0x112>(x);  // row_shr:2
    x = dpp_fmin<0x114>(x);  // row_shr:4
    x = dpp_fmin<0x118>(x);  // row_shr:8
    x = dpp_fmin<0x142>(x);  // row_bcast:15
    x = dpp_fmin<0x143>(x);  // row_bcast:31
    return __int_as_float(__builtin_amdgcn_readlane(__float_as_int(x), 63));
}

extern "C" __global__ __launch_bounds__(64)
void lap_solve(const float* __restrict__ C, float* __restrict__ out) {
    extern __shared__ float rowc[];          // [NROWS_LDS][256]
    const int lane = threadIdx.x;
    const int base = lane * 4;               // 1-based columns base+1..base+4
    const int boff = base * 4 - 1024;        // (row<<10)+boff = byte off of ((row-1)*256+base)

    {   // stage rows 1..NROWS_LDS of C into LDS (exact f32 copy)
        const float4* src = (const float4*)C;
        float4*       dst = (float4*)rowc;
        #pragma unroll 8
        for (int idx = lane; idx < NROWS_LDS * 64; idx += 64) dst[idx] = src[idx];
    }
    __syncthreads();

    // All per-column state in registers (statically indexed):
    float v0 = 0.f, v1 = 0.f, v2 = 0.f, v3 = 0.f;   // col duals v[j]
    float a0 = 0.f, a1 = 0.f, a2 = 0.f, a3 = 0.f;   // a_k = u[p_k]
    int   p0 = 0,  p1 = 0,  p2 = 0,  p3 = 0;        // matched row per col (0 = free)

    // prologue: row 1 (always LDS-resident)
    float4 r = *(const float4*)((const char*)rowc + ((1 << 10) + boff));

    for (int i = 1; i <= NN; ++i) {
        // m doubles as the masked key: used slots are forced to BIGF and q
        // guards every write, so m behaves exactly like where(used,BIG,minv).
        float m0 = BIGF, m1 = BIGF, m2 = BIGF, m3 = BIGF;
        int   w0 = 0, w1 = 0, w2 = 0, w3 = 0;              // way (pred col)
        int   q0 = 0, q1 = 0, q2 = 0, q3 = 0;              // used flags
        float ui = 0.0f;            // u[i] accumulator (fresh row => 0)
        float u0 = 0.0f;            // u[i0] for current step (row i => 0)
        int   j0 = 0, jF = 0;

        for (int guard = 0; guard < 300; ++guard) {
            // cur = (C1[i0][j] - u[i0]) - v[j]  (exact reference op order)
            float c0 = (r.x - u0) - v0;
            float c1 = (r.y - u0) - v1;
            float c2 = (r.z - u0) - v2;
            float c3 = (r.w - u0) - v3;
            if (!q0 && c0 < m0) { m0 = c0; w0 = j0; }
            if (!q1 && c1 < m1) { m1 = c1; w1 = j0; }
            if (!q2 && c2 < m2) { m2 = c2; w2 = j0; }
            if (!q3 && c3 < m3) { m3 = c3; w3 = j0; }

            // local min (index pick runs parallel with the DPP chain)
            float bv = fminf(fminf(m0, m1), fminf(m2, m3));
            int   bk = (m0 == bv) ? 0 : (m1 == bv) ? 1 : (m2 == bv) ? 2 : 3;
            int   rc = (bk == 0) ? p0 : (bk == 1) ? p1 : (bk == 2) ? p2 : p3;
            float ra = (bk == 0) ? a0 : (bk == 1) ? a1 : (bk == 2) ? a2 : a3;
            int   bj = base + bk + 1;
            int   rcs = rc << 10;                   // candidate row byte-offset

            // wave min + lowest-lane winner = argmin first-index semantics
            float gmin = wave_min_bcast(bv);
            unsigned long long bal = __ballot(bv == gmin);
            int wl = (int)__builtin_ctzll(bal | 0x8000000000000000ULL);

            // FIRST: winner row offset -> issue next load ASAP
            int rowoff = __builtin_amdgcn_readlane(rcs, wl);
            int ro = rowoff ? rowoff : 1024;        // clamp when winner col free
            float4 rn;
            if (ro <= NROWS_LDS * 1024)
                rn = *(const float4*)((const char*)rowc + (ro + boff));
            else
                rn = *(const float4*)((const char*)C + (ro + boff));

            // rest of the broadcast + dual updates hide under the load
            int   j1  = __builtin_amdgcn_readlane(bj, wl);
            float u0n = __int_as_float(__builtin_amdgcn_readlane(__float_as_int(ra), wl));

            float delta = gmin;                     // exact reference updates
            if (q0) { a0 += delta; v0 -= delta; } else { m0 -= delta; }
            if (q1) { a1 += delta; v1 -= delta; } else { m1 -= delta; }
            if (q2) { a2 += delta; v2 -= delta; } else { m2 -= delta; }
            if (q3) { a3 += delta; v3 -= delta; } else { m3 -= delta; }
            ui += delta;                            // col 0 (row i) used each step

            // winner becomes used from next step; force its key to BIG
            int oj = (j1 - 1) >> 2, sj = (j1 - 1) & 3;
            if (lane == oj) {
                if (sj == 0)      { q0 = 1; m0 = BIGF; }
                else if (sj == 1) { q1 = 1; m1 = BIGF; }
                else if (sj == 2) { q2 = 1; m2 = BIGF; }
                else              { q3 = 1; m3 = BIGF; }
            }

            j0 = j1; u0 = u0n; r = rn;
            if (rowoff == 0) { jF = j1; break; }    // winner column is free
        }

        // prefetch next outer iteration's row before the augment walk
        {
            int ni = (i < NN) ? (i + 1) : NN;
            int off = (ni << 10) + boff;
            if (ni <= NROWS_LDS) r = *(const float4*)((const char*)rowc + off);
            else                 r = *(const float4*)((const char*)C + off);
        }

        // augment: j is wave-uniform -> readlane (not ds_bpermute) per hop
        int j = jF;
        for (int g2 = 0; g2 < 300 && j != 0; ++g2) {
            int oj = (j - 1) >> 2, sj = (j - 1) & 3;
            int wsel = (sj == 0) ? w0 : (sj == 1) ? w1 : (sj == 2) ? w2 : w3;
            int jn = __builtin_amdgcn_readlane(wsel, oj);
            int pn; float an;
            if (jn == 0) { pn = i; an = ui; }
            else {
                int on = (jn - 1) >> 2, sn = (jn - 1) & 3;
                int   ps = (sn == 0) ? p0 : (sn == 1) ? p1 : (sn == 2) ? p2 : p3;
                float as = (sn == 0) ? a0 : (sn == 1) ? a1 : (sn == 2) ? a2 : a3;
                pn = __builtin_amdgcn_readlane(ps, on);
                an = __int_as_float(__builtin_amdgcn_readlane(__float_as_int(as), on));
            }
            if (lane == oj) {
                if (sj == 0)      { p0 = pn; a0 = an; }
                else if (sj == 1) { p1 = pn; a1 = an; }
                else if (sj == 2) { p2 = pn; a2 = an; }
                else              { p3 = pn; a3 = an; }
            }
            j = jn;
        }
    }

    // emit 0/1 labelling: out[p[j]-1, j-1] = 1  (out pre-zeroed by memset)
    if (p0) out[(p0 - 1) * NN + base + 0] = 1.0f;
    if (p1) out[(p1 - 1) * NN + base + 1] = 1.0f;
    if (p2) out[(p2 - 1) * NN + base + 2] = 1.0f;
    if (p3) out[(p3 - 1) * NN + base + 3] = 1.0f;
}

extern "C" void kernel_launch(void* const* d_in, const int* in_sizes, int n_in,
                              void* d_out, int out_size, void* d_ws, size_t ws_size,
                              hipStream_t stream) {
    const float* C   = (const float*)d_in[0];
    float*       out = (float*)d_out;

    static_assert(SMEM_BYTES <= 160 * 1024, "LDS budget");
    (void)hipFuncSetAttribute((const void*)lap_solve,
                              hipFuncAttributeMaxDynamicSharedMemorySize,
                              SMEM_BYTES);

    hipMemsetAsync(out, 0, NN * NN * sizeof(float), stream);
    lap_solve<<<dim3(1), dim3(64), SMEM_BYTES, stream>>>(C, out);
}